// Round 4
// baseline (497.914 us; speedup 1.0000x reference)
//
#include <hip/hip_runtime.h>
#include <cmath>

// Problem constants: S=16384, IN_DIM=1024, D=6400, BINS=20
#define S_DIM 16384
#define K_DIM 1024
#define D_DIM 6400
#define NBINS 20
#define HSTRIDE 21    // per-col stride in histogram (21: odd -> bank-permuting)
#define QSTRIDE 5377  // per-quad copy stride (5377%32==1 -> +quad bank shift)

using half_t = _Float16;
using half8  = __attribute__((ext_vector_type(8))) _Float16;
using f32x4  = __attribute__((ext_vector_type(4))) float;

// ---------------- fp32 -> fp16 convert + d_out zeroing (one launch) -------
__global__ void cvt_f32_f16(const float* __restrict__ a, half_t* __restrict__ da, int n8a,
                            const float* __restrict__ b, half_t* __restrict__ db, int n8b,
                            float4* __restrict__ z, int nz4) {
  int i = blockIdx.x * blockDim.x + threadIdx.x;
  if (i < nz4) z[i] = (float4){0.f, 0.f, 0.f, 0.f};   // histogram accumulator
  const float* s; half_t* d; int idx;
  if (i < n8a) { s = a; d = da; idx = i; }
  else { idx = i - n8a; if (idx >= n8b) return; s = b; d = db; }
  float4 v0 = ((const float4*)s)[idx * 2];
  float4 v1 = ((const float4*)s)[idx * 2 + 1];
  half8 h = { (half_t)v0.x, (half_t)v0.y, (half_t)v0.z, (half_t)v0.w,
              (half_t)v1.x, (half_t)v1.y, (half_t)v1.z, (half_t)v1.w };
  ((half8*)d)[idx] = h;
}

#define VMWAIT(N) __asm__ volatile("s_waitcnt vmcnt(" #N ")" ::: "memory")
#define LGKM0()   __asm__ volatile("s_waitcnt lgkmcnt(0)" ::: "memory")
#define BAR()     __asm__ volatile("s_barrier" ::: "memory")
#define SP1()     __builtin_amdgcn_s_setprio(1)
#define SP0()     __builtin_amdgcn_s_setprio(0)

#define GLL(SRC, DST) __builtin_amdgcn_global_load_lds(                      \
    (const __attribute__((address_space(1))) void*)(SRC),                    \
    (__attribute__((address_space(3))) void*)(DST), 16, 0, 0)

// ---------------- fused GEMM + histogram, 256x256, 8-wave, B-direct -------
// 512 threads = 8 waves (2M x 4N); per-wave C = 128x64; BK=32; 32 K-tiles,
// fully unrolled (all LDS/global offsets are compile-time immediates).
//
// B OPERANDS BYPASS LDS: lane (l16,quad) loads wh[(colBase+wn*64+fn*16+l16)
// *1024 + t*32 + quad*8] (16B; quads form contiguous 64B lines -> coalesced;
// W col-panels 512KB are L2-resident under the XCD swizzle). Double-buffered
// in regs (bA/bB, 16+16 VGPR), loaded 1 tile ahead.
// A stays LDS-staged (dup x4 across wn): dbuf 2x16KB, 2 GLL/thread/tile.
//   A-read swizzle for 64B rows: chunk = quad ^ ((row>>1)&3); per 8-lane
//   group the (row&1, chunk) slots are all 8 distinct -> conflict-free.
//   Staging inverse on the global source; GLL dest stays linear.
// Per tile: P0: [VMW(2): retire B(t), keep A(t+1)] [issue B(t+1) x4]
//               [8 ds_read aF] [MFMA mf0-3 x fn0-3] [lgkm(0)] [BAR]
//           P1: [2 GLL A(t+2) -> buf(t&1)] [MFMA mf4-7] [VMW(6): retire
//               A(t+1), keep B(t+1)4+A(t+2)2] [BAR]
// WAR: stage A(t+2) hits buf[t&1], read this tile at P0; lgkm(0) before the
// mid-BAR drains every wave's reads before any wave issues the stage.
// RAW: A(t+1) retired by VMW(6) + BAR before t+1's reads.
// Tail: t=30 -> W1=VMW(4); t=31 -> W0=VMW(0), no stage/loads.
// B-loads cannot reorder across the mid-BAR (asm memory clobber), so the
// counted vmcnt sets are exact.
//
// Histogram: 4 quad-private LDS copies (QSTRIDE%32==1 -> quad shifts banks);
// contention drops from 4 lanes/address to 2 (wm pair). ldsA 32KB + hist
// 84KB = 118.8KB LDS.
__global__ __launch_bounds__(512, 2) void gemm_hist256(
    const half_t* __restrict__ xh, const half_t* __restrict__ wh,
    const float* __restrict__ mins, const float* __restrict__ maxs,
    int* __restrict__ ghist)
{
  __shared__ __align__(16) char ldsA[2 * 16384];   // 2 bufs x 256 rows x 64 B
  __shared__ int shist4[4 * QSTRIDE];              // 4 quad-private copies

  const int t    = threadIdx.x;
  const int lane = t & 63;
  const int wv   = t >> 6;
  const int wm   = wv >> 2;          // 0..1
  const int wn   = wv & 3;           // 0..3
  const int l16  = lane & 15;
  const int quad = lane >> 4;

  // XCD-aware bijective swizzle: 1600 blocks = 8 XCDs x 200.
  // Consecutive wg share the col-tile -> W panel L2-resident per XCD.
  const int bid = blockIdx.x;
  const int wg  = (bid & 7) * 200 + (bid >> 3);
  const int ct  = wg / 64;                 // 0..24 col-tiles
  const int rt  = wg - ct * 64;            // 0..63 row-tiles
  const int colBase = ct * 256;
  const int rowBase = rt * 256;

  for (int i = t; i < 4 * QSTRIDE; i += 512) shist4[i] = 0;

  // A fragment read base (row = wm*128 + mf*16 + l16; chunk = quad^((row>>1)&3);
  // mf*16 and wm*128 don't change (row>>1)&3).
  const char* pA = ldsA + (wm * 128 + l16) * 64 + ((quad ^ ((l16 >> 1) & 3)) * 16);

  // A staging: thread t owns linear slot t*16B (row r0=t>>2, slot-chunk t&3);
  // fetches global chunk (t&3)^((r0>>1)&3) = (t&3)^((t>>3)&3).
  const int r0   = t >> 2;
  const int gOff = r0 * K_DIM + (((t & 3) ^ ((t >> 3) & 3)) * 8);  // elements
  const int wvD  = wv * 1024;   // wave-uniform LDS base (HW adds lane*16)
  const half_t* xS  = xh + (size_t)rowBase * K_DIM + gOff;
  const half_t* xS2 = xS + 128 * K_DIM;    // rows 128..255

  // B direct-load bases (per fn); tile offset (t+1)*32 elems = 64B imm.
  const half_t* wBp[4];
#pragma unroll
  for (int fn = 0; fn < 4; ++fn)
    wBp[fn] = wh + (size_t)(colBase + wn * 64 + fn * 16 + l16) * K_DIM + quad * 8;

  f32x4 acc[8][4];
#pragma unroll
  for (int m = 0; m < 8; ++m)
#pragma unroll
    for (int n = 0; n < 4; ++n) acc[m][n] = (f32x4){0.f, 0.f, 0.f, 0.f};

  half8 aF[8], bA[4], bB[4];

  // Prologue: B(0) -> bA; stage A(0)->buf0, A(1)->buf1.
  // Outstanding: B0(4),A0(2),A1(2); VMW(2) retires B0+A0, keeps A1.
#pragma unroll
  for (int fn = 0; fn < 4; ++fn) bA[fn] = *(const half8*)(wBp[fn]);
  GLL(xS,       ldsA + wvD);
  GLL(xS2,      ldsA + 8192 + wvD);
  GLL(xS + 32,  ldsA + 16384 + wvD);
  GLL(xS2 + 32, ldsA + 16384 + 8192 + wvD);
  VMWAIT(2); BAR();

#define TILE(TT, BC, BN_, W0, W1, DOB, DOS)                                  \
  {                                                                          \
    W0;                                                                      \
    if (DOB) {                                                               \
      _Pragma("unroll") for (int fn = 0; fn < 4; ++fn)                       \
        BN_[fn] = *(const half8*)(wBp[fn] + ((TT) + 1) * 32);                \
    }                                                                        \
    _Pragma("unroll") for (int mf = 0; mf < 8; ++mf)                         \
      aF[mf] = *(const half8*)(pA + ((TT) & 1) * 16384 + mf * 1024);         \
    SP1();                                                                   \
    _Pragma("unroll") for (int mf = 0; mf < 4; ++mf)                         \
      _Pragma("unroll") for (int fn = 0; fn < 4; ++fn)                       \
        acc[mf][fn] = __builtin_amdgcn_mfma_f32_16x16x32_f16(                \
            aF[mf], BC[fn], acc[mf][fn], 0, 0, 0);                           \
    SP0();                                                                   \
    LGKM0(); BAR();                                                          \
    if (DOS) {                                                               \
      GLL(xS  + ((TT) + 2) * 32, ldsA + ((TT) & 1) * 16384 + wvD);           \
      GLL(xS2 + ((TT) + 2) * 32, ldsA + ((TT) & 1) * 16384 + 8192 + wvD);    \
    }                                                                        \
    SP1();                                                                   \
    _Pragma("unroll") for (int mf = 4; mf < 8; ++mf)                         \
      _Pragma("unroll") for (int fn = 0; fn < 4; ++fn)                       \
        acc[mf][fn] = __builtin_amdgcn_mfma_f32_16x16x32_f16(                \
            aF[mf], BC[fn], acc[mf][fn], 0, 0, 0);                           \
    SP0();                                                                   \
    W1; BAR();                                                               \
  }

#define PAIR(T0)                                                             \
  TILE(T0,       bA, bB, VMWAIT(2), VMWAIT(6), 1, 1)                         \
  TILE((T0) + 1, bB, bA, VMWAIT(2), VMWAIT(6), 1, 1)

  PAIR(0)  PAIR(2)  PAIR(4)  PAIR(6)  PAIR(8)
  PAIR(10) PAIR(12) PAIR(14) PAIR(16) PAIR(18)
  PAIR(20) PAIR(22) PAIR(24) PAIR(26) PAIR(28)
  TILE(30, bA, bB, VMWAIT(2), VMWAIT(4), 1, 0)
  TILE(31, bB, bA, VMWAIT(0), (void)0,   0, 0)

#undef PAIR
#undef TILE

  // Epilogue: bin 128 values/thread into this quad's private histogram.
  // torch.histc semantics: count iff min<=v<=max; v==max -> last bin.
#pragma unroll
  for (int nf = 0; nf < 4; ++nf) {
    const int lc = wn * 64 + nf * 16 + l16;
    const float a = mins[colBase + lc], b = maxs[colBase + lc];
    const float sc = (float)NBINS / (b - a);
    int* colHist = &shist4[quad * QSTRIDE + lc * HSTRIDE];
#pragma unroll
    for (int mf = 0; mf < 8; ++mf) {
#pragma unroll
      for (int r = 0; r < 4; ++r) {
        float v = acc[mf][nf][r];
        if (v >= a && v <= b) {
          int bin = (int)((v - a) * sc);          // (v-a)>=0 -> trunc==floor
          bin = bin > NBINS - 1 ? NBINS - 1 : bin;
          atomicAdd(&colHist[bin], 1);
        }
      }
    }
  }
  __syncthreads();
  for (int i = t; i < 256 * NBINS; i += 512) {
    int col = i / NBINS, bin = i - col * NBINS;
    int base = col * HSTRIDE + bin;
    int v = shist4[base] + shist4[QSTRIDE + base] +
            shist4[2 * QSTRIDE + base] + shist4[3 * QSTRIDE + base];
    if (v) atomicAdd(&ghist[colBase * NBINS + i], v);
  }
}

// ---------------- fallback (no workspace): fp32-staged 128x128 tile -------
__global__ __launch_bounds__(256) void gemm_hist_fb(
    const float* __restrict__ xf, const float* __restrict__ wf,
    const float* __restrict__ mins, const float* __restrict__ maxs,
    int* __restrict__ ghist)
{
  __shared__ __align__(16) half_t ldsA[4096];
  __shared__ __align__(16) half_t ldsB[4096];
  __shared__ int shist[128 * HSTRIDE];

  const int t     = threadIdx.x;
  const int lane  = t & 63;
  const int wv    = t >> 6;
  const int waveM = wv >> 1;
  const int waveN = wv & 1;
  const int l16   = lane & 15;
  const int quad  = lane >> 4;
  const int colBase = blockIdx.x * 128;

  for (int i = t; i < 128 * HSTRIDE; i += 256) shist[i] = 0;

  float mn[4], mx[4], inv[4];
  int lcol[4];
#pragma unroll
  for (int nt = 0; nt < 4; ++nt) {
    int lc = waveN * 64 + nt * 16 + l16;
    lcol[nt] = lc;
    float a = mins[colBase + lc], b = maxs[colBase + lc];
    mn[nt] = a; mx[nt] = b;
    inv[nt] = (float)NBINS / (b - a);
  }

  int aOff[4], bOff[4];
#pragma unroll
  for (int mt = 0; mt < 4; ++mt) {
    int m = waveM * 64 + mt * 16 + l16;
    aOff[mt] = (m * 4 + (quad ^ ((m >> 1) & 3))) * 8;
  }
#pragma unroll
  for (int nt = 0; nt < 4; ++nt) {
    int n = waveN * 64 + nt * 16 + l16;
    bOff[nt] = (n * 4 + (quad ^ ((n >> 1) & 3))) * 8;
  }

  for (int rt = blockIdx.y; rt < S_DIM / 128; rt += gridDim.y) {
    const int rowBase = rt * 128;
    f32x4 acc[4][4];
#pragma unroll
    for (int mt = 0; mt < 4; ++mt)
#pragma unroll
      for (int nt = 0; nt < 4; ++nt) acc[mt][nt] = (f32x4){0.f, 0.f, 0.f, 0.f};

    for (int kt = 0; kt < K_DIM; kt += 32) {
      __syncthreads();
#pragma unroll
      for (int i = 0; i < 2; ++i) {
        const int seg = t + i * 256;
        const int row = seg >> 2;
        const int kch = (seg & 3) ^ ((row >> 1) & 3);
        const float* ga = xf + (size_t)(rowBase + row) * K_DIM + kt + kch * 8;
        float4 v0 = ((const float4*)ga)[0];
        float4 v1 = ((const float4*)ga)[1];
        half8 h = { (half_t)v0.x, (half_t)v0.y, (half_t)v0.z, (half_t)v0.w,
                    (half_t)v1.x, (half_t)v1.y, (half_t)v1.z, (half_t)v1.w };
        *(half8*)&ldsA[seg * 8] = h;
        const float* gb = wf + (size_t)(colBase + row) * K_DIM + kt + kch * 8;
        float4 u0 = ((const float4*)gb)[0];
        float4 u1 = ((const float4*)gb)[1];
        half8 g = { (half_t)u0.x, (half_t)u0.y, (half_t)u0.z, (half_t)u0.w,
                    (half_t)u1.x, (half_t)u1.y, (half_t)u1.z, (half_t)u1.w };
        *(half8*)&ldsB[seg * 8] = g;
      }
      __syncthreads();
      {
        half8 aFf[4], bFf[4];
#pragma unroll
        for (int mt = 0; mt < 4; ++mt) aFf[mt] = *(const half8*)&ldsA[aOff[mt]];
#pragma unroll
        for (int nt = 0; nt < 4; ++nt) bFf[nt] = *(const half8*)&ldsB[bOff[nt]];
#pragma unroll
        for (int mt = 0; mt < 4; ++mt)
#pragma unroll
          for (int nt = 0; nt < 4; ++nt)
            acc[mt][nt] = __builtin_amdgcn_mfma_f32_16x16x32_f16(
                aFf[mt], bFf[nt], acc[mt][nt], 0, 0, 0);
      }
    }

#pragma unroll
    for (int nt = 0; nt < 4; ++nt) {
      const float a = mn[nt], b = mx[nt], sc = inv[nt];
      int* colHist = &shist[lcol[nt] * HSTRIDE];
#pragma unroll
      for (int mt = 0; mt < 4; ++mt) {
#pragma unroll
        for (int r = 0; r < 4; ++r) {
          float v = acc[mt][nt][r];
          if (v >= a && v <= b) {
            int bin = (int)((v - a) * sc);
            bin = bin > NBINS - 1 ? NBINS - 1 : bin;
            atomicAdd(&colHist[bin], 1);
          }
        }
      }
    }
  }

  __syncthreads();
  for (int i = t; i < 128 * NBINS; i += 256) {
    int col = i / NBINS, bin = i - col * NBINS;
    int v = shist[col * HSTRIDE + bin];
    if (v) atomicAdd(&ghist[colBase * NBINS + i], v);
  }
}

// ---------------- L2 normalize per group of 20 bins (in place) ------------
__global__ void normalize_kernel(const int* __restrict__ hist, float* __restrict__ out) {
  int g = blockIdx.x * blockDim.x + threadIdx.x;
  if (g >= D_DIM) return;
  const int base = g * NBINS;
  float v[NBINS];
  float ss = 0.f;
#pragma unroll
  for (int i = 0; i < NBINS; ++i) { v[i] = (float)hist[base + i]; ss += v[i] * v[i]; }
  float sc = 1.0f / fmaxf(sqrtf(ss), 1e-12f);
#pragma unroll
  for (int i = 0; i < NBINS; ++i) out[base + i] = v[i] * sc;
}

extern "C" void kernel_launch(void* const* d_in, const int* in_sizes, int n_in,
                              void* d_out, int out_size, void* d_ws, size_t ws_size,
                              hipStream_t stream) {
  const float* x    = (const float*)d_in[0];
  const float* W    = (const float*)d_in[1];
  const float* mins = (const float*)d_in[2];
  const float* maxs = (const float*)d_in[3];
  float* out = (float*)d_out;

  const size_t xh_elems = (size_t)S_DIM * K_DIM;
  const size_t wh_elems = (size_t)D_DIM * K_DIM;
  const size_t need = (xh_elems + wh_elems) * sizeof(half_t);

  if (ws_size >= need) {
    half_t* xh = (half_t*)d_ws;
    half_t* wh = xh + xh_elems;
    int n8x = (int)(xh_elems / 8), n8w = (int)(wh_elems / 8);
    int tot = n8x + n8w;
    // cvt also zeroes d_out (re-poisoned 0xAA between runs)
    cvt_f32_f16<<<(tot + 255) / 256, 256, 0, stream>>>(
        x, xh, n8x, W, wh, n8w, (float4*)d_out, out_size / 4);
    gemm_hist256<<<dim3(1600), 512, 0, stream>>>(xh, wh, mins, maxs, (int*)d_out);
  } else {
    hipMemsetAsync(d_out, 0, (size_t)out_size * sizeof(float), stream);
    gemm_hist_fb<<<dim3(D_DIM / 128, 64), 256, 0, stream>>>(
        x, W, mins, maxs, (int*)d_out);
  }

  normalize_kernel<<<(D_DIM + 255) / 256, 256, 0, stream>>>((int*)d_out, out);
}

// Round 6
// 370.999 us; speedup vs baseline: 1.3421x; 1.3421x over previous
//
#include <hip/hip_runtime.h>
#include <cmath>

// Problem constants: S=16384, IN_DIM=1024, D=6400, BINS=20
#define S_DIM 16384
#define K_DIM 1024
#define D_DIM 6400
#define NBINS 20
#define HSTRIDE 21   // shist column stride (pad 20->21: spreads banks)

using half_t = _Float16;
using half8  = __attribute__((ext_vector_type(8))) _Float16;
using f32x4  = __attribute__((ext_vector_type(4))) float;

// ---------------- fp32 -> fp16 convert + d_out zeroing (one launch) -------
__global__ void cvt_f32_f16(const float* __restrict__ a, half_t* __restrict__ da, int n8a,
                            const float* __restrict__ b, half_t* __restrict__ db, int n8b,
                            float4* __restrict__ z, int nz4) {
  int i = blockIdx.x * blockDim.x + threadIdx.x;
  if (i < nz4) z[i] = (float4){0.f, 0.f, 0.f, 0.f};   // histogram accumulator
  const float* s; half_t* d; int idx;
  if (i < n8a) { s = a; d = da; idx = i; }
  else { idx = i - n8a; if (idx >= n8b) return; s = b; d = db; }
  float4 v0 = ((const float4*)s)[idx * 2];
  float4 v1 = ((const float4*)s)[idx * 2 + 1];
  half8 h = { (half_t)v0.x, (half_t)v0.y, (half_t)v0.z, (half_t)v0.w,
              (half_t)v1.x, (half_t)v1.y, (half_t)v1.z, (half_t)v1.w };
  ((half8*)d)[idx] = h;
}

#define VMWAIT(N) __asm__ volatile("s_waitcnt vmcnt(" #N ")" ::: "memory")
#define BAR()     __asm__ volatile("s_barrier" ::: "memory")
#define SP1()     __builtin_amdgcn_s_setprio(1)
#define SP0()     __builtin_amdgcn_s_setprio(0)

#define GLL(SRC, DST) __builtin_amdgcn_global_load_lds(                      \
    (const __attribute__((address_space(1))) void*)(SRC),                    \
    (__attribute__((address_space(3))) void*)(DST), 16, 0, 0)

// ------------- fused GEMM + histogram, 256x256, 16-wave, pipelined --------
// 1024 threads = 16 waves (4M x 4N); per-wave C = 64x64; BK=32.
// acc 64 (AGPR) + frags 32 + addressing ~12 -> ~110 regs/wave <= 128
// => 4 waves/SIMD from one block (2x occupancy vs the 8-wave/256-reg R3).
// K-loop is a runtime loop (2 tiles/iter, compile-time buffer parities
// inside) + 2 peeled drain tiles -- semantics identical to the fully
// unrolled form, ~13x smaller code (compile-time/regalloc hardening).
//
// Pipeline (R3's proven liveness schedule, ks collapsed), per tile:
//   P0: read bHi(t)           ; MFMA Q00(aLo,bLo)
//   P1: read aHi(t)           ; MFMA Q01(aLo,bHi) ; VMW(1) [retire A(t+1),
//                               keep B(t+1); per-tile issue order is A,B]; BAR
//   P2: read aLo(t+1) [buf^1] ; MFMA Q11(aHi,bHi) ; VMW(0) [B(t+1) landed;
//                               issued 1.5 tiles earlier -> covered] ; BAR
//   P3: stage {A,B}(t+2)->buf[t&1] ; MFMA Q10(aHi,bLo) ; read bLo(t+1)
// WAR: the P3 stage overwrites buf[t&1]; every wave's reads of it (bHi@P0
// consumed by Q01 before the P1-end BAR, aHi@P1 consumed by Q11 before the
// P2-end BAR) are complete before any wave passes the P2-end BAR and issues
// the stage. RAW: A(t+1) retired by VMW(1)+BAR before its P2 read; B(t+1)
// by VMW(0)+BAR before its P3 read.
// LDS swizzle (64B rows, 4x16B chunks): reader chunk = quad ^ ((l16>>1)&3);
// per 8-lane group the (row-parity, chunk) pairs are all distinct ->
// conflict-free. Staging applies the inverse on the GLOBAL source
// (g = (t&3)^((t>>3)&3)); GLL dest stays linear (both-sides-or-neither).
__global__ __launch_bounds__(1024, 4) void gemm_hist256(
    const half_t* __restrict__ xh, const half_t* __restrict__ wh,
    const float* __restrict__ mins, const float* __restrict__ maxs,
    int* __restrict__ ghist)
{
  __shared__ __align__(16) char ldsA[2 * 16384];   // 2 bufs x 256 rows x 64 B
  __shared__ __align__(16) char ldsB[2 * 16384];
  __shared__ int shist[256 * HSTRIDE];             // 21.5 KB

  const int t    = threadIdx.x;
  const int lane = t & 63;
  const int wv   = t >> 6;           // 0..15
  const int wm   = wv >> 2;          // 0..3
  const int wn   = wv & 3;           // 0..3
  const int l16  = lane & 15;
  const int quad = lane >> 4;

  // XCD-aware bijective swizzle: 1600 blocks = 8 XCDs x 200
  const int bid = blockIdx.x;
  const int wg  = (bid & 7) * 200 + (bid >> 3);
  const int ct  = wg / 64;                 // 0..24 col-tiles
  const int rt  = wg - ct * 64;            // 0..63 row-tiles
  const int colBase = ct * 256;
  const int rowBase = rt * 256;

  for (int i = t; i < 256 * HSTRIDE; i += 1024) shist[i] = 0;

  // Fragment read bases. Row = (wm|wn)*64 + f*16 + l16; swizzled chunk =
  // quad ^ ((row>>1)&3) = quad ^ ((l16>>1)&3) (f*16, w*64 don't touch bits).
  const int swz = (quad ^ ((l16 >> 1) & 3)) * 16;
  const char* pA = ldsA + (wm * 64 + l16) * 64 + swz;
  const char* pB = ldsB + (wn * 64 + l16) * 64 + swz;

  // Staging: thread t owns linear slot (row r0 = t>>2, chunk t&3) = byte
  // t*16; fetches global chunk g = (t&3)^((r0>>1)&3) = (t&3)^((t>>3)&3).
  const int r0   = t >> 2;                                   // 0..255
  const int gOff = r0 * K_DIM + (((t & 3) ^ ((t >> 3) & 3)) * 8);  // elements
  const int wvD  = wv * 1024;   // wave-uniform LDS base (HW adds lane*16)

  const half_t* xS = xh + (size_t)rowBase * K_DIM + gOff;
  const half_t* wS = wh + (size_t)colBase * K_DIM + gOff;

  f32x4 acc[4][4];
#pragma unroll
  for (int m = 0; m < 4; ++m)
#pragma unroll
    for (int n = 0; n < 4; ++n) acc[m][n] = (f32x4){0.f, 0.f, 0.f, 0.f};

  half8 aLo[2], aHi[2], bLo[2], bHi[2];

#define MFMA4(AH, BH, MO, NO)                                                \
  _Pragma("unroll") for (int m2 = 0; m2 < 2; ++m2)                           \
  _Pragma("unroll") for (int n2 = 0; n2 < 2; ++n2)                           \
    acc[(MO) + m2][(NO) + n2] = __builtin_amdgcn_mfma_f32_16x16x32_f16(      \
        AH[m2], BH[n2], acc[(MO) + m2][(NO) + n2], 0, 0, 0);

  // Prologue: stage {A,B}(0)->buf0, {A,B}(1)->buf1 (A before B each tile);
  // VMW(2) retires tile 0, keeps tile 1 in flight; then preload tile-0 frags.
  GLL(xS,      ldsA + wvD);
  GLL(wS,      ldsB + wvD);
  GLL(xS + 32, ldsA + 16384 + wvD);
  GLL(wS + 32, ldsB + 16384 + wvD);
  VMWAIT(2); BAR();
  aLo[0] = *(const half8*)(pA);  aLo[1] = *(const half8*)(pA + 1024);
  bLo[0] = *(const half8*)(pB);  bLo[1] = *(const half8*)(pB + 1024);

  // Loop-carried staging pointers: at tile TT they point at k-offset
  // (TT+2)*32 elements (tile TT stages tile TT+2); advance +32 per tile.
  const half_t* xStg = xS + 64;
  const half_t* wStg = wS + 64;

  // PB = current tile's buffer, PN = next tile's. RDA: read aLo(t+1)@P2.
  // RDB: read bLo(t+1)@P3. STG: stage t+2. W1A: the P1-end wait.
#define TILE(PB, PN, RDA, RDB, STG, W1A)                                     \
  {                                                                          \
    bHi[0] = *(const half8*)(pB + (PB) + 2048);                              \
    bHi[1] = *(const half8*)(pB + (PB) + 3072);                              \
    SP1(); MFMA4(aLo, bLo, 0, 0); SP0();                                     \
    aHi[0] = *(const half8*)(pA + (PB) + 2048);                              \
    aHi[1] = *(const half8*)(pA + (PB) + 3072);                              \
    SP1(); MFMA4(aLo, bHi, 0, 2); SP0();                                     \
    W1A; BAR();                                                              \
    if (RDA) {                                                               \
      aLo[0] = *(const half8*)(pA + (PN));                                   \
      aLo[1] = *(const half8*)(pA + (PN) + 1024);                            \
    }                                                                        \
    SP1(); MFMA4(aHi, bHi, 2, 2); SP0();                                     \
    VMWAIT(0); BAR();                                                        \
    if (STG) {                                                               \
      GLL(xStg, ldsA + (PB) + wvD);                                          \
      GLL(wStg, ldsB + (PB) + wvD);                                          \
      xStg += 32; wStg += 32;                                                \
    }                                                                        \
    SP1(); MFMA4(aHi, bLo, 2, 0); SP0();                                     \
    if (RDB) {                                                               \
      bLo[0] = *(const half8*)(pB + (PN));                                   \
      bLo[1] = *(const half8*)(pB + (PN) + 1024);                            \
    }                                                                        \
  }

  // Tiles 0..29 (15 iterations x 2); tile 29 stages tile 31 (last).
#pragma unroll 1
  for (int it = 0; it < 15; ++it) {
    TILE(0,     16384, 1, 1, 1, VMWAIT(1));
    TILE(16384, 0,     1, 1, 1, VMWAIT(1));
  }
  TILE(0,     16384, 1, 1, 0, VMWAIT(1));   // tile 30: nothing left to stage
  TILE(16384, 0,     0, 0, 0, VMWAIT(0));   // tile 31: compute only

#undef TILE

  // Epilogue: bin 64 values/thread. torch.histc semantics: count iff
  // min<=v<=max; v==max -> last bin (trunc==floor since v-a>=0).
#pragma unroll
  for (int nf = 0; nf < 4; ++nf) {
    const int lc = wn * 64 + nf * 16 + l16;
    const float a = mins[colBase + lc], b = maxs[colBase + lc];
    const float sc = (float)NBINS / (b - a);
    int* colHist = &shist[lc * HSTRIDE];
#pragma unroll
    for (int mf = 0; mf < 4; ++mf) {
#pragma unroll
      for (int r = 0; r < 4; ++r) {
        float v = acc[mf][nf][r];
        if (v >= a && v <= b) {
          int bin = (int)((v - a) * sc);
          bin = bin > NBINS - 1 ? NBINS - 1 : bin;
          atomicAdd(&colHist[bin], 1);
        }
      }
    }
  }
  __syncthreads();
  for (int i = t; i < 256 * NBINS; i += 1024) {
    int col = i / NBINS, bin = i - col * NBINS;
    int v = shist[col * HSTRIDE + bin];
    if (v) atomicAdd(&ghist[colBase * NBINS + i], v);
  }
}

// ---------------- fallback (no workspace): fp32-staged 128x128 tile -------
__global__ __launch_bounds__(256) void gemm_hist_fb(
    const float* __restrict__ xf, const float* __restrict__ wf,
    const float* __restrict__ mins, const float* __restrict__ maxs,
    int* __restrict__ ghist)
{
  __shared__ __align__(16) half_t ldsA[4096];
  __shared__ __align__(16) half_t ldsB[4096];
  __shared__ int shist[128 * HSTRIDE];

  const int t     = threadIdx.x;
  const int lane  = t & 63;
  const int wv    = t >> 6;
  const int waveM = wv >> 1;
  const int waveN = wv & 1;
  const int l16   = lane & 15;
  const int quad  = lane >> 4;
  const int colBase = blockIdx.x * 128;

  for (int i = t; i < 128 * HSTRIDE; i += 256) shist[i] = 0;

  float mn[4], mx[4], inv[4];
  int lcol[4];
#pragma unroll
  for (int nt = 0; nt < 4; ++nt) {
    int lc = waveN * 64 + nt * 16 + l16;
    lcol[nt] = lc;
    float a = mins[colBase + lc], b = maxs[colBase + lc];
    mn[nt] = a; mx[nt] = b;
    inv[nt] = (float)NBINS / (b - a);
  }

  int aOff[4], bOff[4];
#pragma unroll
  for (int mt = 0; mt < 4; ++mt) {
    int m = waveM * 64 + mt * 16 + l16;
    aOff[mt] = (m * 4 + (quad ^ ((m >> 1) & 3))) * 8;
  }
#pragma unroll
  for (int nt = 0; nt < 4; ++nt) {
    int n = waveN * 64 + nt * 16 + l16;
    bOff[nt] = (n * 4 + (quad ^ ((n >> 1) & 3))) * 8;
  }

  for (int rt = blockIdx.y; rt < S_DIM / 128; rt += gridDim.y) {
    const int rowBase = rt * 128;
    f32x4 acc[4][4];
#pragma unroll
    for (int mt = 0; mt < 4; ++mt)
#pragma unroll
      for (int nt = 0; nt < 4; ++nt) acc[mt][nt] = (f32x4){0.f, 0.f, 0.f, 0.f};

    for (int kt = 0; kt < K_DIM; kt += 32) {
      __syncthreads();
#pragma unroll
      for (int i = 0; i < 2; ++i) {
        const int seg = t + i * 256;
        const int row = seg >> 2;
        const int kch = (seg & 3) ^ ((row >> 1) & 3);
        const float* ga = xf + (size_t)(rowBase + row) * K_DIM + kt + kch * 8;
        float4 v0 = ((const float4*)ga)[0];
        float4 v1 = ((const float4*)ga)[1];
        half8 h = { (half_t)v0.x, (half_t)v0.y, (half_t)v0.z, (half_t)v0.w,
                    (half_t)v1.x, (half_t)v1.y, (half_t)v1.z, (half_t)v1.w };
        *(half8*)&ldsA[seg * 8] = h;
        const float* gb = wf + (size_t)(colBase + row) * K_DIM + kt + kch * 8;
        float4 u0 = ((const float4*)gb)[0];
        float4 u1 = ((const float4*)gb)[1];
        half8 g = { (half_t)u0.x, (half_t)u0.y, (half_t)u0.z, (half_t)u0.w,
                    (half_t)u1.x, (half_t)u1.y, (half_t)u1.z, (half_t)u1.w };
        *(half8*)&ldsB[seg * 8] = g;
      }
      __syncthreads();
      {
        half8 aFf[4], bFf[4];
#pragma unroll
        for (int mt = 0; mt < 4; ++mt) aFf[mt] = *(const half8*)&ldsA[aOff[mt]];
#pragma unroll
        for (int nt = 0; nt < 4; ++nt) bFf[nt] = *(const half8*)&ldsB[bOff[nt]];
#pragma unroll
        for (int mt = 0; mt < 4; ++mt)
#pragma unroll
          for (int nt = 0; nt < 4; ++nt)
            acc[mt][nt] = __builtin_amdgcn_mfma_f32_16x16x32_f16(
                aFf[mt], bFf[nt], acc[mt][nt], 0, 0, 0);
      }
    }

#pragma unroll
    for (int nt = 0; nt < 4; ++nt) {
      const float a = mn[nt], b = mx[nt], sc = inv[nt];
      int* colHist = &shist[lcol[nt] * HSTRIDE];
#pragma unroll
      for (int mt = 0; mt < 4; ++mt) {
#pragma unroll
        for (int r = 0; r < 4; ++r) {
          float v = acc[mt][nt][r];
          if (v >= a && v <= b) {
            int bin = (int)((v - a) * sc);
            bin = bin > NBINS - 1 ? NBINS - 1 : bin;
            atomicAdd(&colHist[bin], 1);
          }
        }
      }
    }
  }

  __syncthreads();
  for (int i = t; i < 128 * NBINS; i += 256) {
    int col = i / NBINS, bin = i - col * NBINS;
    int v = shist[col * HSTRIDE + bin];
    if (v) atomicAdd(&ghist[colBase * NBINS + i], v);
  }
}

// ---------------- L2 normalize per group of 20 bins (in place) ------------
__global__ void normalize_kernel(const int* __restrict__ hist, float* __restrict__ out) {
  int g = blockIdx.x * blockDim.x + threadIdx.x;
  if (g >= D_DIM) return;
  const int base = g * NBINS;
  float v[NBINS];
  float ss = 0.f;
#pragma unroll
  for (int i = 0; i < NBINS; ++i) { v[i] = (float)hist[base + i]; ss += v[i] * v[i]; }
  float sc = 1.0f / fmaxf(sqrtf(ss), 1e-12f);
#pragma unroll
  for (int i = 0; i < NBINS; ++i) out[base + i] = v[i] * sc;
}

extern "C" void kernel_launch(void* const* d_in, const int* in_sizes, int n_in,
                              void* d_out, int out_size, void* d_ws, size_t ws_size,
                              hipStream_t stream) {
  const float* x    = (const float*)d_in[0];
  const float* W    = (const float*)d_in[1];
  const float* mins = (const float*)d_in[2];
  const float* maxs = (const float*)d_in[3];
  float* out = (float*)d_out;

  const size_t xh_elems = (size_t)S_DIM * K_DIM;
  const size_t wh_elems = (size_t)D_DIM * K_DIM;
  const size_t need = (xh_elems + wh_elems) * sizeof(half_t);

  if (ws_size >= need) {
    half_t* xh = (half_t*)d_ws;
    half_t* wh = xh + xh_elems;
    int n8x = (int)(xh_elems / 8), n8w = (int)(wh_elems / 8);
    int tot = n8x + n8w;
    // cvt also zeroes d_out (re-poisoned 0xAA between runs)
    cvt_f32_f16<<<(tot + 255) / 256, 256, 0, stream>>>(
        x, xh, n8x, W, wh, n8w, (float4*)d_out, out_size / 4);
    gemm_hist256<<<dim3(1600), 1024, 0, stream>>>(xh, wh, mins, maxs, (int*)d_out);
  } else {
    hipMemsetAsync(d_out, 0, (size_t)out_size * sizeof(float), stream);
    gemm_hist_fb<<<dim3(D_DIM / 128, 64), 256, 0, stream>>>(
        x, W, mins, maxs, (int*)d_out);
  }

  normalize_kernel<<<(D_DIM + 255) / 256, 256, 0, stream>>>((int*)d_out, out);
}